// Round 3
// baseline (1832.188 us; speedup 1.0000x reference)
//
#include <hip/hip_runtime.h>
#include <math.h>

#define NU      256
#define NLAYERS 6
#define NBATCH  32768
#define NDIN    784
#define NDOUT   10
#define NUSQ    65536

typedef unsigned short u16;
typedef __attribute__((ext_vector_type(8))) short s16x8;
typedef __attribute__((ext_vector_type(4))) short s16x4;
typedef __attribute__((ext_vector_type(4))) float f32x4;

// bf16 helpers (RNE)
__device__ __forceinline__ u16 f2bf(float x) {
    union { float f; unsigned u; } a; a.f = x;
    const unsigned r = a.u + 0x7fffu + ((a.u >> 16) & 1u);
    return (u16)(r >> 16);
}
__device__ __forceinline__ float bf2f(u16 h) {
    union { unsigned u; float f; } a; a.u = ((unsigned)h) << 16; return a.f;
}

// async global->LDS, 16 B per lane (m97 pattern; LDS dest = wave base + lane*16)
__device__ __forceinline__ void gl_lds16(const u16* g, u16* l) {
    __builtin_amdgcn_global_load_lds(
        (const __attribute__((address_space(1))) void*)g,
        (__attribute__((address_space(3))) void*)l, 16, 0, 0);
}

// uniform-lane float readlane (lane index must be wave-uniform)
__device__ __forceinline__ float rlf(float v, int lane) {
    return __int_as_float(__builtin_amdgcn_readlane(__float_as_int(v), lane));
}

// packed argmax key: |v| bits (top 24) | row (8 bits). unsigned-max == argmax.
__device__ __forceinline__ unsigned pkey(float v, int row) {
    return (__float_as_uint(fabsf(v)) & 0xFFFFFF00u) | (unsigned)row;
}

__device__ __forceinline__ unsigned wave_umax64(unsigned key) {
#pragma unroll
    for (int off = 1; off < 64; off <<= 1) {
        const unsigned o = (unsigned)__shfl_xor((int)key, off);
        key = key > o ? key : o;
    }
    return key;
}

// 16-way static-index dispatch over a wave-uniform column index.
#define COL_CASES16(BODY) \
    case 0:  BODY(0);  break; case 1:  BODY(1);  break; \
    case 2:  BODY(2);  break; case 3:  BODY(3);  break; \
    case 4:  BODY(4);  break; case 5:  BODY(5);  break; \
    case 6:  BODY(6);  break; case 7:  BODY(7);  break; \
    case 8:  BODY(8);  break; case 9:  BODY(9);  break; \
    case 10: BODY(10); break; case 11: BODY(11); break; \
    case 12: BODY(12); break; case 13: BODY(13); break; \
    case 14: BODY(14); break; case 15: BODY(15); break;

// ---------------------------------------------------------------------------
// Fused first kernel, 1024 threads/block.
//   blocks 0..5   : GJ inversion, 16 waves, each wave owns 16 columns
//                   (a[16][4] = 64 VGPR/thread; 4 waves/SIMD latency hiding)
//   blocks 6..517 : in_gemm, 512 active threads (8 waves/CU active density,
//                   same as the previous 2x512-thread-block config)
// Phase-1 pivot argmax: packed u32 key (|v|bits|row) + 6-level shfl_xor
// butterfly (proven correct in an earlier passing run), pivot value
// recovered via one readlane.
// ---------------------------------------------------------------------------
__global__ __launch_bounds__(1024, 1) void fused_inv_ingemm(
    const float* __restrict__ B0, const float* __restrict__ qg,
    u16* __restrict__ wnnh, u16* __restrict__ wnnl,
    u16* __restrict__ wnth, u16* __restrict__ wntl,
    float* __restrict__ bq,
    const float* __restrict__ X, const float* __restrict__ Win,
    const float* __restrict__ bin,
    u16* __restrict__ V0h, u16* __restrict__ V0l,
    u16* __restrict__ V1h, u16* __restrict__ V1l)
{
    // ---- invert LDS ----
    __shared__ __align__(16) float colv[2][256];
    __shared__ int   s_p[2];
    __shared__ float s_pv[2];
    __shared__ int   pivrow[256];
    __shared__ int   ilogrow[256];
    __shared__ float qs[256];
    __shared__ float part[16][256];
    // ---- in_gemm LDS ----
    __shared__ __align__(16) float As[16][128];
    __shared__ __align__(16) float Bs[16][128];

    const int tid = threadIdx.x;

    if (blockIdx.x < NLAYERS) {
        // =================== inversion path ===================
        const int layer = blockIdx.x;
        const int ct = tid & 63;     // lane: owns rows ct*4 .. ct*4+3
        const int wv = tid >> 6;     // wave 0..15: owns cols wv*16 .. wv*16+15

        float a[16][4];
        const float* Ablk = B0 + (size_t)layer * NU * NU;
#pragma unroll
        for (int j = 0; j < 4; ++j) {
            const float* rp = Ablk + (size_t)(ct*4 + j)*NU + wv*16;
#pragma unroll
            for (int i = 0; i < 16; i += 4) {
                const float4 v = *(const float4*)(rp + i);
                a[i+0][j] = v.x; a[i+1][j] = v.y; a[i+2][j] = v.z; a[i+3][j] = v.w;
            }
        }

        int used = 0;

        for (int k = 0; k < 256; ++k) {
            const int wvk = k >> 4, ikk = k & 15, buf = k & 1;

            if (wv == wvk) {
                float c0, c1, c2, c3;
#define EXT(I) { c0 = a[I][0]; c1 = a[I][1]; c2 = a[I][2]; c3 = a[I][3]; }
                switch (ikk) { COL_CASES16(EXT) }
#undef EXT
                unsigned key = (used & 1) ? 0u : pkey(c0, ct*4 + 0);
                unsigned q1  = (used & 2) ? 0u : pkey(c1, ct*4 + 1); key = key > q1 ? key : q1;
                unsigned q2  = (used & 4) ? 0u : pkey(c2, ct*4 + 2); key = key > q2 ? key : q2;
                unsigned q3  = (used & 8) ? 0u : pkey(c3, ct*4 + 3); key = key > q3 ? key : q3;
                key = wave_umax64(key);
                const int pn = __builtin_amdgcn_readfirstlane((int)(key & 255u));
                float bv;
                switch (pn & 3) {
                    case 0: bv = rlf(c0, pn >> 2); break;
                    case 1: bv = rlf(c1, pn >> 2); break;
                    case 2: bv = rlf(c2, pn >> 2); break;
                    default: bv = rlf(c3, pn >> 2); break;
                }
                float4 cw; cw.x = c0; cw.y = c1; cw.z = c2; cw.w = c3;
                *(float4*)(&colv[buf][ct*4]) = cw;
                if (ct == 0) {
                    s_p[buf] = pn;
                    s_pv[buf] = 1.0f / bv;
                    pivrow[k] = pn;
                }
            }
            __syncthreads();

            const int   p      = __builtin_amdgcn_readfirstlane(s_p[buf]);
            const float pivinv = s_pv[buf];
            const int ctp = p >> 2, jp = p & 3;

            const float4 dv = *(const float4*)(&colv[buf][ct*4]);

            float t[16];
#define SEL(J) { _Pragma("unroll") for (int i = 0; i < 16; ++i) t[i] = a[i][J]; }
            switch (jp) {
                case 0: SEL(0) break; case 1: SEL(1) break;
                case 2: SEL(2) break; default: SEL(3) break;
            }
#undef SEL
            float prw[16];
#pragma unroll
            for (int i = 0; i < 16; ++i) prw[i] = __shfl(t[i], ctp) * pivinv;

            if (wv == wvk) {   // column-k special case ONLY in the owning wave
#define ZCOL(I) { prw[I] = pivinv; a[I][0] = 0.0f; a[I][1] = 0.0f; a[I][2] = 0.0f; a[I][3] = 0.0f; }
                switch (ikk) { COL_CASES16(ZCOL) }
#undef ZCOL
            }

            const float d0 = -dv.x, d1 = -dv.y, d2 = -dv.z, d3 = -dv.w;
#pragma unroll
            for (int i = 0; i < 16; ++i) {
                const float pw = prw[i];
                a[i][0] = fmaf(d0, pw, a[i][0]);
                a[i][1] = fmaf(d1, pw, a[i][1]);
                a[i][2] = fmaf(d2, pw, a[i][2]);
                a[i][3] = fmaf(d3, pw, a[i][3]);
            }

            const bool mine = (ct == ctp);
#define OWR(J) { _Pragma("unroll") for (int i = 0; i < 16; ++i) a[i][J] = mine ? prw[i] : a[i][J]; }
            switch (jp) {
                case 0: OWR(0) break; case 1: OWR(1) break;
                case 2: OWR(2) break; default: OWR(3) break;
            }
#undef OWR
            if (mine) used |= (1 << jp);
        }
        __syncthreads();

        // stored a[i][j] = M[r][c], r = ilog[ct*4+j], c = pivrow[wv*16+i]
        if (tid < 256) { ilogrow[pivrow[tid]] = tid; qs[tid] = qg[(size_t)layer*NU + tid]; }
        __syncthreads();

        // ---- bq = M q ----
        {
            float s0=0.f, s1=0.f, s2=0.f, s3=0.f;
#pragma unroll
            for (int i = 0; i < 16; ++i) {
                const float qq = qs[pivrow[wv*16 + i]];
                s0 = fmaf(a[i][0], qq, s0);
                s1 = fmaf(a[i][1], qq, s1);
                s2 = fmaf(a[i][2], qq, s2);
                s3 = fmaf(a[i][3], qq, s3);
            }
            part[wv][ct*4+0] = s0; part[wv][ct*4+1] = s1;
            part[wv][ct*4+2] = s2; part[wv][ct*4+3] = s3;
        }
        __syncthreads();
        if (tid < 256) {
            float s = 0.f;
#pragma unroll
            for (int w2 = 0; w2 < 16; ++w2) s += part[w2][tid];
            bq[(size_t)layer*NU + ilogrow[tid]] = s;
        }

        // ---- split-bf16 W planes ----
        u16* nh = wnnh + (size_t)layer*NUSQ; u16* nl = wnnl + (size_t)layer*NUSQ;
        u16* th = wnth + (size_t)layer*NUSQ; u16* tl = wntl + (size_t)layer*NUSQ;
#pragma unroll
        for (int j = 0; j < 4; ++j) {
            const int r = ilogrow[ct*4 + j];
#pragma unroll
            for (int i = 0; i < 16; ++i) {
                const int c = pivrow[wv*16 + i];
                const float v = a[i][j];
                const u16 h  = f2bf(v);
                const u16 lo = f2bf(v - bf2f(h));
                th[(size_t)r*NU + c] = h;  tl[(size_t)r*NU + c] = lo;  // wnt[n][k]=M[n][k]
                nh[(size_t)c*NU + r] = h;  nl[(size_t)c*NU + r] = lo;  // wnn[n][k]=M[k][n]
            }
        }
        return;
    }

    // =================== in_gemm path (512 active threads) ===================
    if (tid >= 512) return;   // exited waves free their slots; HW barrier counts rest

    const int bid = blockIdx.x - NLAYERS;
    const int m0 = (bid & 255) * 128;
    const int n0 = (bid >> 8) * 128;
    const int t  = tid;
    const int tx = t & 31, ty = t >> 5;   // micro-tile: 8 rows x 4 cols
    const int K = NDIN;

    float acc[8][4];
#pragma unroll
    for (int i = 0; i < 8; ++i)
#pragma unroll
        for (int j = 0; j < 4; ++j) acc[i][j] = 0.0f;

    const int am = t >> 2;          // 0..127
    const int ak = (t & 3) * 4;     // 0,4,8,12
    const int bk = t >> 5;          // 0..15
    const int bn = (t & 31) * 4;    // 0..124

    for (int k0 = 0; k0 < K; k0 += 16) {
        const float4 a0 = *(const float4*)(X + (size_t)(m0 + am)*K + (k0 + ak));
        As[ak+0][am] = a0.x; As[ak+1][am] = a0.y; As[ak+2][am] = a0.z; As[ak+3][am] = a0.w;
        const float4 b0 = *(const float4*)(Win + (size_t)(k0 + bk)*NU + (n0 + bn));
        *(float4*)(&Bs[bk][bn]) = b0;
        __syncthreads();
#pragma unroll
        for (int kk = 0; kk < 16; ++kk) {
            float af[8], bf[4];
            *(float4*)(af)   = *(const float4*)(&As[kk][ty*8]);
            *(float4*)(af+4) = *(const float4*)(&As[kk][ty*8+4]);
            *(float4*)(bf)   = *(const float4*)(&Bs[kk][tx*4]);
#pragma unroll
            for (int i = 0; i < 8; ++i)
#pragma unroll
                for (int j = 0; j < 4; ++j)
                    acc[i][j] = fmaf(af[i], bf[j], acc[i][j]);
        }
        __syncthreads();
    }

#pragma unroll
    for (int i = 0; i < 8; ++i) {
        const size_t row = m0 + ty*8 + i;
        s16x4 vh, vl, th2, tl2;
#pragma unroll
        for (int j = 0; j < 4; ++j) {
            const float v = acc[i][j] + bin[n0 + tx*4 + j];
            const u16 h  = f2bf(v);
            vh[j] = (short)h; vl[j] = (short)f2bf(v - bf2f(h));
            const float tv = tanhf(v);
            const u16 h2 = f2bf(tv);
            th2[j] = (short)h2; tl2[j] = (short)f2bf(tv - bf2f(h2));
        }
        const size_t o = row*NU + n0 + tx*4;
        *(s16x4*)&V0h[o] = vh; *(s16x4*)&V0l[o] = vl;
        *(s16x4*)&V1h[o] = th2; *(s16x4*)&V1l[o] = tl2;
    }
}

// ---------------------------------------------------------------------------
// Split-bf16 MFMA GEMM: C(32768x256) = alpha * A @ W (+bias). Staging via
// async global_load_lds width=16 (lane-contiguous LDS mapping: thread t <->
// LDS bytes [16t,16t+16) per plane buffer). 128x128 tile, BK=32, 4 waves,
// wave = 64x64 = 4x4 MFMA 16x16x32. Split product hh + hl + lh.
// ---------------------------------------------------------------------------
__global__ __launch_bounds__(256, 2) void gemm_mfma(
    const u16* __restrict__ Ah, const u16* __restrict__ Al,
    const u16* __restrict__ Bh, const u16* __restrict__ Bl,
    u16* __restrict__ Ch, u16* __restrict__ Cl,
    const float* __restrict__ bias, const float alpha)
{
    __shared__ __align__(16) u16 lAh[128*32], lAl[128*32], lBh[128*32], lBl[128*32];
    const int t    = threadIdx.x;
    const int lane = t & 63;
    const int w    = t >> 6;
    const int wr = w >> 1, wc = w & 1;
    const int qd = lane >> 4, l15 = lane & 15;
    const int m0 = blockIdx.x * 128, n0 = blockIdx.y * 128;

    const int srow = t >> 2;          // 0..63
    const int skc  = (t & 3) * 8;     // 0,8,16,24

    f32x4 acc[4][4];
    const f32x4 z = {0.f, 0.f, 0.f, 0.f};
#pragma unroll
    for (int i = 0; i < 4; ++i)
#pragma unroll
        for (int j = 0; j < 4; ++j) acc[i][j] = z;

    for (int k0 = 0; k0 < NU; k0 += 32) {
#pragma unroll
        for (int half = 0; half < 2; ++half) {
            const int rr = srow + half*64;
            const size_t ga = (size_t)(m0 + rr)*NU + k0 + skc;
            const size_t gb = (size_t)(n0 + rr)*NU + k0 + skc;
            const int lo = rr*32 + skc;
            gl_lds16(Ah + ga, &lAh[lo]);
            gl_lds16(Al + ga, &lAl[lo]);
            gl_lds16(Bh + gb, &lBh[lo]);
            gl_lds16(Bl + gb, &lBl[lo]);
        }
        __syncthreads();

        s16x8 ah[4], al[4], bh[4], bl[4];
#pragma unroll
        for (int mt = 0; mt < 4; ++mt) {
            const int off = (wr*64 + mt*16 + l15)*32 + qd*8;
            ah[mt] = *(const s16x8*)&lAh[off];
            al[mt] = *(const s16x8*)&lAl[off];
        }
#pragma unroll
        for (int nt = 0; nt < 4; ++nt) {
            const int off = (wc*64 + nt*16 + l15)*32 + qd*8;
            bh[nt] = *(const s16x8*)&lBh[off];
            bl[nt] = *(const s16x8*)&lBl[off];
        }
#pragma unroll
        for (int mt = 0; mt < 4; ++mt)
#pragma unroll
            for (int nt = 0; nt < 4; ++nt) {
                acc[mt][nt] = __builtin_amdgcn_mfma_f32_16x16x32_bf16(ah[mt], bh[nt], acc[mt][nt], 0, 0, 0);
                acc[mt][nt] = __builtin_amdgcn_mfma_f32_16x16x32_bf16(ah[mt], bl[nt], acc[mt][nt], 0, 0, 0);
                acc[mt][nt] = __builtin_amdgcn_mfma_f32_16x16x32_bf16(al[mt], bh[nt], acc[mt][nt], 0, 0, 0);
            }
        __syncthreads();
    }

#pragma unroll
    for (int mt = 0; mt < 4; ++mt) {
#pragma unroll
        for (int nt = 0; nt < 4; ++nt) {
            const int col = n0 + wc*64 + nt*16 + l15;
            const float bb = bias ? bias[col] : 0.0f;
#pragma unroll
            for (int r = 0; r < 4; ++r) {
                const int row = m0 + wr*64 + mt*16 + qd*4 + r;
                const float v = alpha*acc[mt][nt][r] + bb;
                const u16 h  = f2bf(v);
                const u16 lo = f2bf(v - bf2f(h));
                const size_t o = (size_t)row*NU + col;
                Ch[o] = h; Cl[o] = lo;
            }
        }
    }
}

// ---------------------------------------------------------------------------
// out = V0 @ W_out + b_out, N=10. One wave per batch row; V0 from planes.
// ---------------------------------------------------------------------------
__global__ __launch_bounds__(256) void out_gemm(
    const u16* __restrict__ V0h, const u16* __restrict__ V0l,
    const float* __restrict__ Wout,
    const float* __restrict__ bout, float* __restrict__ out)
{
    __shared__ float Ws[NU*NDOUT];
    const int t = threadIdx.x;
    for (int i = t; i < NU*NDOUT; i += 256) Ws[i] = Wout[i];
    __syncthreads();
    const int lane = t & 63;
    const int wv = t >> 6;
    const int row = blockIdx.x*4 + wv;
    float acc[NDOUT];
#pragma unroll
    for (int j = 0; j < NDOUT; ++j) acc[j] = 0.0f;
#pragma unroll
    for (int s = 0; s < 4; ++s) {
        const int k = lane + 64*s;
        const size_t o = (size_t)row*NU + k;
        const float v = bf2f(V0h[o]) + bf2f(V0l[o]);
#pragma unroll
        for (int j = 0; j < NDOUT; ++j) acc[j] = fmaf(v, Ws[k*NDOUT + j], acc[j]);
    }
#pragma unroll
    for (int off = 32; off > 0; off >>= 1) {
#pragma unroll
        for (int j = 0; j < NDOUT; ++j) acc[j] += __shfl_down(acc[j], off);
    }
    if (lane == 0) {
#pragma unroll
        for (int j = 0; j < NDOUT; ++j) out[(size_t)row*NDOUT + j] = acc[j] + bout[j];
    }
}

extern "C" void kernel_launch(void* const* d_in, const int* in_sizes, int n_in,
                              void* d_out, int out_size, void* d_ws, size_t ws_size,
                              hipStream_t stream)
{
    const float* x    = (const float*)d_in[0];
    const float* Win  = (const float*)d_in[1];
    const float* bin  = (const float*)d_in[2];
    const float* B0   = (const float*)d_in[3];
    const float* q    = (const float*)d_in[4];
    const float* Wout = (const float*)d_in[5];
    const float* bout = (const float*)d_in[6];
    float* out = (float*)d_out;

    // workspace carve (~104 MB)
    u16* wnnh = (u16*)d_ws;
    u16* wnnl = wnnh + (size_t)NLAYERS*NUSQ;
    u16* wnth = wnnl + (size_t)NLAYERS*NUSQ;
    u16* wntl = wnth + (size_t)NLAYERS*NUSQ;
    float* bq = (float*)(wntl + (size_t)NLAYERS*NUSQ);
    u16* pl   = (u16*)(bq + NLAYERS*NU);
    const size_t PSZ = (size_t)NBATCH*NU;
    u16* sAh = pl;           u16* sAl = sAh + PSZ;   // slot A (V0)
    u16* sBh = sAl + PSZ;    u16* sBl = sBh + PSZ;   // slot B (V1)
    u16* sCh = sBl + PSZ;    u16* sCl = sCh + PSZ;   // slot C (free)

    // fused: 6 invert blocks + 512 in_gemm blocks, concurrent, 1024 thr
    fused_inv_ingemm<<<NLAYERS + 512, 1024, 0, stream>>>(
        B0, q, wnnh, wnnl, wnth, wntl, bq,
        x, Win, bin, sAh, sAl, sBh, sBl);

    const dim3 ggrid(NBATCH/128, NU/128);   // 256 x 2

    u16 *v0h = sAh, *v0l = sAl, *v1h = sBh, *v1l = sBl, *frh = sCh, *frl = sCl;
    for (int l = 0; l < NLAYERS; ++l) {
        const size_t wo = (size_t)l*NUSQ;
        // newV0 = -V1 @ M
        gemm_mfma<<<ggrid, 256, 0, stream>>>(v1h, v1l, wnnh + wo, wnnl + wo,
                                             frh, frl, nullptr, -1.0f);
        // newV1 = V0 @ M^T + (Mq)^T
        gemm_mfma<<<ggrid, 256, 0, stream>>>(v0h, v0l, wnth + wo, wntl + wo,
                                             v1h, v1l, bq + (size_t)l*NU, 1.0f);
        u16* t0 = v0h; u16* t1 = v0l;
        v0h = frh; v0l = frl; frh = t0; frl = t1;
    }
    out_gemm<<<NBATCH/4, 256, 0, stream>>>(v0h, v0l, Wout, bout, out);
}

// Round 4
// 1747.881 us; speedup vs baseline: 1.0482x; 1.0482x over previous
//
#include <hip/hip_runtime.h>
#include <math.h>

#define NU      256
#define NLAYERS 6
#define NBATCH  32768
#define NDIN    784
#define NDOUT   10
#define NUSQ    65536

typedef unsigned short u16;
typedef __attribute__((ext_vector_type(8))) short s16x8;
typedef __attribute__((ext_vector_type(4))) float f32x4;

// bf16 helpers (RNE)
__device__ __forceinline__ u16 f2bf(float x) {
    union { float f; unsigned u; } a; a.f = x;
    const unsigned r = a.u + 0x7fffu + ((a.u >> 16) & 1u);
    return (u16)(r >> 16);
}
__device__ __forceinline__ float bf2f(u16 h) {
    union { unsigned u; float f; } a; a.u = ((unsigned)h) << 16; return a.f;
}

// async global->LDS, 16 B per lane (m97 pattern; LDS dest = wave base + lane*16)
__device__ __forceinline__ void gl_lds16(const u16* g, u16* l) {
    __builtin_amdgcn_global_load_lds(
        (const __attribute__((address_space(1))) void*)g,
        (__attribute__((address_space(3))) void*)l, 16, 0, 0);
}

// uniform-lane float readlane (lane index must be wave-uniform)
__device__ __forceinline__ float rlf(float v, int lane) {
    return __int_as_float(__builtin_amdgcn_readlane(__float_as_int(v), lane));
}

// packed argmax key: |v| bits (top 24) | row (8 bits). unsigned-max == argmax.
__device__ __forceinline__ unsigned pkey(float v, int row) {
    return (__float_as_uint(fabsf(v)) & 0xFFFFFF00u) | (unsigned)row;
}

__device__ __forceinline__ unsigned wave_umax64(unsigned key) {
#pragma unroll
    for (int off = 1; off < 64; off <<= 1) {
        const unsigned o = (unsigned)__shfl_xor((int)key, off);
        key = key > o ? key : o;
    }
    return key;
}

// 32-way static-index dispatch over a wave-uniform column index.
#define COL_CASES(BODY) \
    case 0:  BODY(0);  break; case 1:  BODY(1);  break; \
    case 2:  BODY(2);  break; case 3:  BODY(3);  break; \
    case 4:  BODY(4);  break; case 5:  BODY(5);  break; \
    case 6:  BODY(6);  break; case 7:  BODY(7);  break; \
    case 8:  BODY(8);  break; case 9:  BODY(9);  break; \
    case 10: BODY(10); break; case 11: BODY(11); break; \
    case 12: BODY(12); break; case 13: BODY(13); break; \
    case 14: BODY(14); break; case 15: BODY(15); break; \
    case 16: BODY(16); break; case 17: BODY(17); break; \
    case 18: BODY(18); break; case 19: BODY(19); break; \
    case 20: BODY(20); break; case 21: BODY(21); break; \
    case 22: BODY(22); break; case 23: BODY(23); break; \
    case 24: BODY(24); break; case 25: BODY(25); break; \
    case 26: BODY(26); break; case 27: BODY(27); break; \
    case 28: BODY(28); break; case 29: BODY(29); break; \
    case 30: BODY(30); break; case 31: BODY(31); break;

// ---------------------------------------------------------------------------
// Fused first kernel: blocks 0..5 = GJ inversion (panel-local, 16 barriers
// total instead of 256); blocks 6..517 = in_gemm (r0-proven fp32 body).
//
// Panel scheme (math identical to the proven per-step GJ, rescheduled):
//   8 panels of 32 columns, wave p owns panel p (r0 layout: a[32][4]).
//   F phase (owner wave only, NO barriers): 32 micro-steps. Per step:
//     packed-key argmax over unused rows (r1-proven butterfly), build
//     g = col*pivinv with pivot element 1-pivinv  (then  v' = v - g*v[r]
//     reproduces both the rank-1 update AND the pivot-row scaling),
//     publish g (LDS) + pivot row, update own 32 columns via readlane.
//   barrier; U phase: other 7 waves batch-replay the 32 steps from LDS
//   (same sequential math; readlane instead of ds_bpermute); barrier.
// ---------------------------------------------------------------------------
__global__ __launch_bounds__(512, 2) void fused_inv_ingemm(
    const float* __restrict__ B0, const float* __restrict__ qg,
    u16* __restrict__ wnnh, u16* __restrict__ wnnl,
    u16* __restrict__ wnth, u16* __restrict__ wntl,
    float* __restrict__ bq,
    const float* __restrict__ X, const float* __restrict__ Win,
    const float* __restrict__ bin,
    u16* __restrict__ V0h, u16* __restrict__ V0l,
    u16* __restrict__ V1h, u16* __restrict__ V1l)
{
    // ---- invert LDS ----
    __shared__ __align__(16) float g_lds[32][256];
    __shared__ int   pivrow[256];
    __shared__ int   ilogrow[256];
    __shared__ float qs[256];
    __shared__ float part[8][256];
    // ---- in_gemm LDS ----
    __shared__ __align__(16) float As[16][128];
    __shared__ __align__(16) float Bs[16][128];

    const int tid = threadIdx.x;

    if (blockIdx.x < NLAYERS) {
        // =================== inversion path ===================
        const int layer = blockIdx.x;
        const int ct = tid & 63;     // lane: owns rows ct*4 .. ct*4+3
        const int wv = tid >> 6;     // wave: owns cols wv*32 .. wv*32+31

        float a[32][4];
        const float* Ablk = B0 + (size_t)layer * NU * NU;
#pragma unroll
        for (int j = 0; j < 4; ++j) {
            const float* rp = Ablk + (size_t)(ct*4 + j)*NU + wv*32;
#pragma unroll
            for (int i = 0; i < 32; i += 4) {
                const float4 v = *(const float4*)(rp + i);
                a[i+0][j] = v.x; a[i+1][j] = v.y; a[i+2][j] = v.z; a[i+3][j] = v.w;
            }
        }

        int used = 0;

        for (int p = 0; p < 8; ++p) {
            const int k0 = p * 32;

            if (wv == p) {
                // ---------- F: local factorization of own 32 columns ----------
                for (int kk = 0; kk < 32; ++kk) {
                    float c0, c1, c2, c3;
#define EXT(I) { c0 = a[I][0]; c1 = a[I][1]; c2 = a[I][2]; c3 = a[I][3]; }
                    switch (kk) { COL_CASES(EXT) }
#undef EXT
                    unsigned key = (used & 1) ? 0u : pkey(c0, ct*4 + 0);
                    unsigned q1  = (used & 2) ? 0u : pkey(c1, ct*4 + 1); key = key > q1 ? key : q1;
                    unsigned q2  = (used & 4) ? 0u : pkey(c2, ct*4 + 2); key = key > q2 ? key : q2;
                    unsigned q3  = (used & 8) ? 0u : pkey(c3, ct*4 + 3); key = key > q3 ? key : q3;
                    key = wave_umax64(key);
                    const int pn  = __builtin_amdgcn_readfirstlane((int)(key & 255u));
                    const int ctp = pn >> 2, jp = pn & 3;
                    float bv;
                    switch (jp) {
                        case 0: bv = rlf(c0, ctp); break;
                        case 1: bv = rlf(c1, ctp); break;
                        case 2: bv = rlf(c2, ctp); break;
                        default: bv = rlf(c3, ctp); break;
                    }
                    const float pivinv = 1.0f / bv;
                    const bool mine = (ct == ctp);

                    float g0 = c0*pivinv, g1 = c1*pivinv, g2 = c2*pivinv, g3 = c3*pivinv;
                    if (mine) {
                        switch (jp) {
                            case 0: g0 = 1.0f - pivinv; break;
                            case 1: g1 = 1.0f - pivinv; break;
                            case 2: g2 = 1.0f - pivinv; break;
                            default: g3 = 1.0f - pivinv; break;
                        }
                    }
                    float4 gw; gw.x = g0; gw.y = g1; gw.z = g2; gw.w = g3;
                    *(float4*)(&g_lds[kk][ct*4]) = gw;
                    if (ct == 0) pivrow[k0 + kk] = pn;

                    // generic update of all own columns: v' = v - g * v[r]
#define UPD(J) { _Pragma("unroll") for (int j = 0; j < 32; ++j) { \
                        const float s = rlf(a[j][J], ctp); \
                        a[j][0] = fmaf(-g0, s, a[j][0]); \
                        a[j][1] = fmaf(-g1, s, a[j][1]); \
                        a[j][2] = fmaf(-g2, s, a[j][2]); \
                        a[j][3] = fmaf(-g3, s, a[j][3]); } }
                    switch (jp) {
                        case 0: UPD(0) break; case 1: UPD(1) break;
                        case 2: UPD(2) break; default: UPD(3) break;
                    }
#undef UPD
                    // column-kk overwrite: exact -g / pivinv form
                    float t0 = -g0, t1 = -g1, t2 = -g2, t3 = -g3;
                    if (mine) {
                        switch (jp) {
                            case 0: t0 = pivinv; break; case 1: t1 = pivinv; break;
                            case 2: t2 = pivinv; break; default: t3 = pivinv; break;
                        }
                    }
#define CKO(I) { a[I][0] = t0; a[I][1] = t1; a[I][2] = t2; a[I][3] = t3; }
                    switch (kk) { COL_CASES(CKO) }
#undef CKO
                    if (mine) used |= (1 << jp);
                }
            }
            __syncthreads();

            if (wv != p) {
                // ---------- U: batch-replay the 32 recorded steps ----------
                for (int kk = 0; kk < 32; ++kk) {
                    const int rk = __builtin_amdgcn_readfirstlane(pivrow[k0 + kk]);
                    const int ctp = rk >> 2, jp = rk & 3;
                    const float4 gv = *(const float4*)(&g_lds[kk][ct*4]);
#define UPDU(J) { _Pragma("unroll") for (int j = 0; j < 32; ++j) { \
                        const float s = rlf(a[j][J], ctp); \
                        a[j][0] = fmaf(-gv.x, s, a[j][0]); \
                        a[j][1] = fmaf(-gv.y, s, a[j][1]); \
                        a[j][2] = fmaf(-gv.z, s, a[j][2]); \
                        a[j][3] = fmaf(-gv.w, s, a[j][3]); } }
                    switch (jp) {
                        case 0: UPDU(0) break; case 1: UPDU(1) break;
                        case 2: UPDU(2) break; default: UPDU(3) break;
                    }
#undef UPDU
                    if (ct == ctp) used |= (1 << jp);
                }
            }
            __syncthreads();
        }

        // stored a[i][j] = M[r][c], r = ilog[ct*4+j], c = pivrow[wv*32+i]
        if (tid < 256) { ilogrow[pivrow[tid]] = tid; qs[tid] = qg[(size_t)layer*NU + tid]; }
        __syncthreads();

        // ---- bq = M q ----
        {
            float s0=0.f, s1=0.f, s2=0.f, s3=0.f;
#pragma unroll
            for (int i = 0; i < 32; ++i) {
                const float qq = qs[pivrow[wv*32 + i]];
                s0 = fmaf(a[i][0], qq, s0);
                s1 = fmaf(a[i][1], qq, s1);
                s2 = fmaf(a[i][2], qq, s2);
                s3 = fmaf(a[i][3], qq, s3);
            }
            part[wv][ct*4+0] = s0; part[wv][ct*4+1] = s1;
            part[wv][ct*4+2] = s2; part[wv][ct*4+3] = s3;
        }
        __syncthreads();
        if (tid < 256) {
            float s = 0.f;
#pragma unroll
            for (int w2 = 0; w2 < 8; ++w2) s += part[w2][tid];
            bq[(size_t)layer*NU + ilogrow[tid]] = s;
        }

        // ---- split-bf16 W planes ----
        u16* nh = wnnh + (size_t)layer*NUSQ; u16* nl = wnnl + (size_t)layer*NUSQ;
        u16* th = wnth + (size_t)layer*NUSQ; u16* tl = wntl + (size_t)layer*NUSQ;
#pragma unroll
        for (int j = 0; j < 4; ++j) {
            const int r = ilogrow[ct*4 + j];
#pragma unroll
            for (int i = 0; i < 32; ++i) {
                const int c = pivrow[wv*32 + i];
                const float v = a[i][j];
                const u16 h  = f2bf(v);
                const u16 lo = f2bf(v - bf2f(h));
                th[(size_t)r*NU + c] = h;  tl[(size_t)r*NU + c] = lo;  // wnt[n][k]=M[n][k]
                nh[(size_t)c*NU + r] = h;  nl[(size_t)c*NU + r] = lo;  // wnn[n][k]=M[k][n]
            }
        }
        return;
    }

    // =================== in_gemm path (256 active threads) ===================
    if (tid >= 256) return;   // exited waves free their slots; HW barrier counts rest

    const int bid = blockIdx.x - NLAYERS;
    const int m0 = (bid & 255) * 128;
    const int n0 = (bid >> 8) * 128;
    const int t  = tid;
    const int tx = t & 15, ty = t >> 4;
    const int K = NDIN;

    float acc[8][8];
#pragma unroll
    for (int i = 0; i < 8; ++i)
#pragma unroll
        for (int j = 0; j < 8; ++j) acc[i][j] = 0.0f;

    const int am = t >> 1;
    const int ak = (t & 1) * 8;
    const int bk = t >> 4;
    const int bn = (t & 15) * 8;

    for (int k0 = 0; k0 < K; k0 += 16) {
        const float* Ap = X + (size_t)(m0 + am)*K + (k0 + ak);
        const float4 a0 = *(const float4*)(Ap);
        const float4 a1 = *(const float4*)(Ap + 4);
        As[ak+0][am] = a0.x; As[ak+1][am] = a0.y; As[ak+2][am] = a0.z; As[ak+3][am] = a0.w;
        As[ak+4][am] = a1.x; As[ak+5][am] = a1.y; As[ak+6][am] = a1.z; As[ak+7][am] = a1.w;
        const float* Bp = Win + (size_t)(k0 + bk)*NU + (n0 + bn);
        const float4 b0 = *(const float4*)(Bp);
        const float4 b1 = *(const float4*)(Bp + 4);
        *(float4*)(&Bs[bk][bn])   = b0;
        *(float4*)(&Bs[bk][bn+4]) = b1;
        __syncthreads();
#pragma unroll
        for (int kk = 0; kk < 16; ++kk) {
            float af[8], bf[8];
            *(float4*)(af)   = *(const float4*)(&As[kk][ty*8]);
            *(float4*)(af+4) = *(const float4*)(&As[kk][ty*8+4]);
            *(float4*)(bf)   = *(const float4*)(&Bs[kk][tx*8]);
            *(float4*)(bf+4) = *(const float4*)(&Bs[kk][tx*8+4]);
#pragma unroll
            for (int i = 0; i < 8; ++i)
#pragma unroll
                for (int j = 0; j < 8; ++j)
                    acc[i][j] = fmaf(af[i], bf[j], acc[i][j]);
        }
        __syncthreads();
    }

#pragma unroll
    for (int i = 0; i < 8; ++i) {
        const size_t row = m0 + ty*8 + i;
        s16x8 vh, vl, th2, tl2;
#pragma unroll
        for (int j = 0; j < 8; ++j) {
            const float v = acc[i][j] + bin[n0 + tx*8 + j];
            const u16 h  = f2bf(v);
            vh[j] = (short)h; vl[j] = (short)f2bf(v - bf2f(h));
            const float tv = tanhf(v);
            const u16 h2 = f2bf(tv);
            th2[j] = (short)h2; tl2[j] = (short)f2bf(tv - bf2f(h2));
        }
        const size_t o = row*NU + n0 + tx*8;
        *(s16x8*)&V0h[o] = vh; *(s16x8*)&V0l[o] = vl;
        *(s16x8*)&V1h[o] = th2; *(s16x8*)&V1l[o] = tl2;
    }
}

// ---------------------------------------------------------------------------
// Split-bf16 MFMA GEMM: C(32768x256) = alpha * A @ W (+bias). Staging via
// async global_load_lds width=16 (lane-contiguous LDS mapping: thread t <->
// LDS bytes [16t,16t+16) per plane buffer). 128x128 tile, BK=32, 4 waves,
// wave = 64x64 = 4x4 MFMA 16x16x32. Split product hh + hl + lh.
// ---------------------------------------------------------------------------
__global__ __launch_bounds__(256, 2) void gemm_mfma(
    const u16* __restrict__ Ah, const u16* __restrict__ Al,
    const u16* __restrict__ Bh, const u16* __restrict__ Bl,
    u16* __restrict__ Ch, u16* __restrict__ Cl,
    const float* __restrict__ bias, const float alpha)
{
    __shared__ __align__(16) u16 lAh[128*32], lAl[128*32], lBh[128*32], lBl[128*32];
    const int t    = threadIdx.x;
    const int lane = t & 63;
    const int w    = t >> 6;
    const int wr = w >> 1, wc = w & 1;
    const int qd = lane >> 4, l15 = lane & 15;
    const int m0 = blockIdx.x * 128, n0 = blockIdx.y * 128;

    const int srow = t >> 2;          // 0..63
    const int skc  = (t & 3) * 8;     // 0,8,16,24

    f32x4 acc[4][4];
    const f32x4 z = {0.f, 0.f, 0.f, 0.f};
#pragma unroll
    for (int i = 0; i < 4; ++i)
#pragma unroll
        for (int j = 0; j < 4; ++j) acc[i][j] = z;

    for (int k0 = 0; k0 < NU; k0 += 32) {
#pragma unroll
        for (int half = 0; half < 2; ++half) {
            const int rr = srow + half*64;
            const size_t ga = (size_t)(m0 + rr)*NU + k0 + skc;
            const size_t gb = (size_t)(n0 + rr)*NU + k0 + skc;
            const int lo = rr*32 + skc;
            gl_lds16(Ah + ga, &lAh[lo]);
            gl_lds16(Al + ga, &lAl[lo]);
            gl_lds16(Bh + gb, &lBh[lo]);
            gl_lds16(Bl + gb, &lBl[lo]);
        }
        __syncthreads();

        s16x8 ah[4], al[4], bh[4], bl[4];
#pragma unroll
        for (int mt = 0; mt < 4; ++mt) {
            const int off = (wr*64 + mt*16 + l15)*32 + qd*8;
            ah[mt] = *(const s16x8*)&lAh[off];
            al[mt] = *(const s16x8*)&lAl[off];
        }
#pragma unroll
        for (int nt = 0; nt < 4; ++nt) {
            const int off = (wc*64 + nt*16 + l15)*32 + qd*8;
            bh[nt] = *(const s16x8*)&lBh[off];
            bl[nt] = *(const s16x8*)&lBl[off];
        }
#pragma unroll
        for (int mt = 0; mt < 4; ++mt)
#pragma unroll
            for (int nt = 0; nt < 4; ++nt) {
                acc[mt][nt] = __builtin_amdgcn_mfma_f32_16x16x32_bf16(ah[mt], bh[nt], acc[mt][nt], 0, 0, 0);
                acc[mt][nt] = __builtin_amdgcn_mfma_f32_16x16x32_bf16(ah[mt], bl[nt], acc[mt][nt], 0, 0, 0);
                acc[mt][nt] = __builtin_amdgcn_mfma_f32_16x16x32_bf16(al[mt], bh[nt], acc[mt][nt], 0, 0, 0);
            }
        __syncthreads();
    }

#pragma unroll
    for (int mt = 0; mt < 4; ++mt) {
#pragma unroll
        for (int nt = 0; nt < 4; ++nt) {
            const int col = n0 + wc*64 + nt*16 + l15;
            const float bb = bias ? bias[col] : 0.0f;
#pragma unroll
            for (int r = 0; r < 4; ++r) {
                const int row = m0 + wr*64 + mt*16 + qd*4 + r;
                const float v = alpha*acc[mt][nt][r] + bb;
                const u16 h  = f2bf(v);
                const u16 lo = f2bf(v - bf2f(h));
                const size_t o = (size_t)row*NU + col;
                Ch[o] = h; Cl[o] = lo;
            }
        }
    }
}

// ---------------------------------------------------------------------------
// out = V0 @ W_out + b_out, N=10. One wave per batch row; V0 from planes.
// ---------------------------------------------------------------------------
__global__ __launch_bounds__(256) void out_gemm(
    const u16* __restrict__ V0h, const u16* __restrict__ V0l,
    const float* __restrict__ Wout,
    const float* __restrict__ bout, float* __restrict__ out)
{
    __shared__ float Ws[NU*NDOUT];
    const int t = threadIdx.x;
    for (int i = t; i < NU*NDOUT; i += 256) Ws[i] = Wout[i];
    __syncthreads();
    const int lane = t & 63;
    const int wv = t >> 6;
    const int row = blockIdx.x*4 + wv;
    float acc[NDOUT];
#pragma unroll
    for (int j = 0; j < NDOUT; ++j) acc[j] = 0.0f;
#pragma unroll
    for (int s = 0; s < 4; ++s) {
        const int k = lane + 64*s;
        const size_t o = (size_t)row*NU + k;
        const float v = bf2f(V0h[o]) + bf2f(V0l[o]);
#pragma unroll
        for (int j = 0; j < NDOUT; ++j) acc[j] = fmaf(v, Ws[k*NDOUT + j], acc[j]);
    }
#pragma unroll
    for (int off = 32; off > 0; off >>= 1) {
#pragma unroll
        for (int j = 0; j < NDOUT; ++j) acc[j] += __shfl_down(acc[j], off);
    }
    if (lane == 0) {
#pragma unroll
        for (int j = 0; j < NDOUT; ++j) out[(size_t)row*NDOUT + j] = acc[j] + bout[j];
    }
}

extern "C" void kernel_launch(void* const* d_in, const int* in_sizes, int n_in,
                              void* d_out, int out_size, void* d_ws, size_t ws_size,
                              hipStream_t stream)
{
    const float* x    = (const float*)d_in[0];
    const float* Win  = (const float*)d_in[1];
    const float* bin  = (const float*)d_in[2];
    const float* B0   = (const float*)d_in[3];
    const float* q    = (const float*)d_in[4];
    const float* Wout = (const float*)d_in[5];
    const float* bout = (const float*)d_in[6];
    float* out = (float*)d_out;

    // workspace carve (~104 MB)
    u16* wnnh = (u16*)d_ws;
    u16* wnnl = wnnh + (size_t)NLAYERS*NUSQ;
    u16* wnth = wnnl + (size_t)NLAYERS*NUSQ;
    u16* wntl = wnth + (size_t)NLAYERS*NUSQ;
    float* bq = (float*)(wntl + (size_t)NLAYERS*NUSQ);
    u16* pl   = (u16*)(bq + NLAYERS*NU);
    const size_t PSZ = (size_t)NBATCH*NU;
    u16* sAh = pl;           u16* sAl = sAh + PSZ;   // slot A (V0)
    u16* sBh = sAl + PSZ;    u16* sBl = sBh + PSZ;   // slot B (V1)
    u16* sCh = sBl + PSZ;    u16* sCl = sCh + PSZ;   // slot C (free)

    // fused: 6 invert blocks + 512 in_gemm blocks, concurrent
    fused_inv_ingemm<<<NLAYERS + 512, 512, 0, stream>>>(
        B0, q, wnnh, wnnl, wnth, wntl, bq,
        x, Win, bin, sAh, sAl, sBh, sBl);

    const dim3 ggrid(NBATCH/128, NU/128);   // 256 x 2

    u16 *v0h = sAh, *v0l = sAl, *v1h = sBh, *v1l = sBl, *frh = sCh, *frl = sCl;
    for (int l = 0; l < NLAYERS; ++l) {
        const size_t wo = (size_t)l*NUSQ;
        // newV0 = -V1 @ M
        gemm_mfma<<<ggrid, 256, 0, stream>>>(v1h, v1l, wnnh + wo, wnnl + wo,
                                             frh, frl, nullptr, -1.0f);
        // newV1 = V0 @ M^T + (Mq)^T
        gemm_mfma<<<ggrid, 256, 0, stream>>>(v0h, v0l, wnth + wo, wntl + wo,
                                             v1h, v1l, bq + (size_t)l*NU, 1.0f);
        u16* t0 = v0h; u16* t1 = v0l;
        v0h = frh; v0l = frl; frh = t0; frl = t1;
    }
    out_gemm<<<NBATCH/4, 256, 0, stream>>>(v0h, v0l, Wout, bout, out);
}

// Round 5
// 868.667 us; speedup vs baseline: 2.1092x; 2.0121x over previous
//
#include <hip/hip_runtime.h>
#include <math.h>

#define NU      256
#define NLAYERS 6
#define NBATCH  32768
#define NDIN    784
#define NDOUT   10
#define NUSQ    65536

typedef unsigned short u16;
typedef __attribute__((ext_vector_type(8))) short s16x8;
typedef __attribute__((ext_vector_type(4))) float f32x4;

// bf16 helpers (RNE)
__device__ __forceinline__ u16 f2bf(float x) {
    union { float f; unsigned u; } a; a.f = x;
    const unsigned r = a.u + 0x7fffu + ((a.u >> 16) & 1u);
    return (u16)(r >> 16);
}
__device__ __forceinline__ float bf2f(u16 h) {
    union { unsigned u; float f; } a; a.u = ((unsigned)h) << 16; return a.f;
}

// async global->LDS, 16 B per lane (m97 pattern; LDS dest = wave base + lane*16)
__device__ __forceinline__ void gl_lds16(const u16* g, u16* l) {
    __builtin_amdgcn_global_load_lds(
        (const __attribute__((address_space(1))) void*)g,
        (__attribute__((address_space(3))) void*)l, 16, 0, 0);
}

// uniform-lane float readlane (lane index must be wave-uniform)
__device__ __forceinline__ float rlf(float v, int lane) {
    return __int_as_float(__builtin_amdgcn_readlane(__float_as_int(v), lane));
}

// packed argmax key: |v| bits (top 24) | row (8 bits). unsigned-max == argmax.
__device__ __forceinline__ unsigned pkey(float v, int row) {
    return (__float_as_uint(fabsf(v)) & 0xFFFFFF00u) | (unsigned)row;
}

// wave64 unsigned-max reduce, pure VALU via DPP (no LDS pipe).
// canonical gfx9 sequence: row_shr 1/2/4/8 (prefix-max within 16-lane rows),
// row_bcast15, row_bcast31. Result valid in lane 63.
__device__ __forceinline__ unsigned dpp_umax64_lane63(unsigned key) {
    unsigned t;
    t = (unsigned)__builtin_amdgcn_update_dpp(0, (int)key, 0x111, 0xf, 0xf, false); // row_shr:1
    key = key > t ? key : t;
    t = (unsigned)__builtin_amdgcn_update_dpp(0, (int)key, 0x112, 0xf, 0xf, false); // row_shr:2
    key = key > t ? key : t;
    t = (unsigned)__builtin_amdgcn_update_dpp(0, (int)key, 0x114, 0xf, 0xf, false); // row_shr:4
    key = key > t ? key : t;
    t = (unsigned)__builtin_amdgcn_update_dpp(0, (int)key, 0x118, 0xf, 0xf, false); // row_shr:8
    key = key > t ? key : t;
    t = (unsigned)__builtin_amdgcn_update_dpp(0, (int)key, 0x142, 0xf, 0xf, false); // row_bcast:15
    key = key > t ? key : t;
    t = (unsigned)__builtin_amdgcn_update_dpp(0, (int)key, 0x143, 0xf, 0xf, false); // row_bcast:31
    key = key > t ? key : t;
    return key;
}

// 32-way static-index dispatch over a wave-uniform column index.
#define COL_CASES(BODY) \
    case 0:  BODY(0);  break; case 1:  BODY(1);  break; \
    case 2:  BODY(2);  break; case 3:  BODY(3);  break; \
    case 4:  BODY(4);  break; case 5:  BODY(5);  break; \
    case 6:  BODY(6);  break; case 7:  BODY(7);  break; \
    case 8:  BODY(8);  break; case 9:  BODY(9);  break; \
    case 10: BODY(10); break; case 11: BODY(11); break; \
    case 12: BODY(12); break; case 13: BODY(13); break; \
    case 14: BODY(14); break; case 15: BODY(15); break; \
    case 16: BODY(16); break; case 17: BODY(17); break; \
    case 18: BODY(18); break; case 19: BODY(19); break; \
    case 20: BODY(20); break; case 21: BODY(21); break; \
    case 22: BODY(22); break; case 23: BODY(23); break; \
    case 24: BODY(24); break; case 25: BODY(25); break; \
    case 26: BODY(26); break; case 27: BODY(27); break; \
    case 28: BODY(28); break; case 29: BODY(29); break; \
    case 30: BODY(30); break; case 31: BODY(31); break;

// ---------------------------------------------------------------------------
// Fused first kernel: blocks 0..5 = GJ inversion (r0-proven structure with
// the per-step DS traffic removed: DPP argmax + readlane broadcast);
// blocks 6..517 = in_gemm (r0-proven fp32 body, threads>=256 exit).
// ---------------------------------------------------------------------------
__global__ __launch_bounds__(512, 2) void fused_inv_ingemm(
    const float* __restrict__ B0, const float* __restrict__ qg,
    u16* __restrict__ wnnh, u16* __restrict__ wnnl,
    u16* __restrict__ wnth, u16* __restrict__ wntl,
    float* __restrict__ bq,
    const float* __restrict__ X, const float* __restrict__ Win,
    const float* __restrict__ bin,
    u16* __restrict__ V0h, u16* __restrict__ V0l,
    u16* __restrict__ V1h, u16* __restrict__ V1l)
{
    // ---- invert LDS ----
    __shared__ __align__(16) float colv[2][256];
    __shared__ int   s_p[2];
    __shared__ float s_pv[2];
    __shared__ int   pivrow[256];
    __shared__ int   ilogrow[256];
    __shared__ float qs[256];
    __shared__ float part[8][256];
    // ---- in_gemm LDS ----
    __shared__ __align__(16) float As[16][128];
    __shared__ __align__(16) float Bs[16][128];

    const int tid = threadIdx.x;

    if (blockIdx.x < NLAYERS) {
        // =================== inversion path ===================
        const int layer = blockIdx.x;
        const int ct = tid & 63;     // lane: owns rows ct*4 .. ct*4+3
        const int wv = tid >> 6;     // wave: owns cols wv*32 .. wv*32+31

        float a[32][4];
        const float* Ablk = B0 + (size_t)layer * NU * NU;
#pragma unroll
        for (int j = 0; j < 4; ++j) {
            const float* rp = Ablk + (size_t)(ct*4 + j)*NU + wv*32;
#pragma unroll
            for (int i = 0; i < 32; i += 4) {
                const float4 v = *(const float4*)(rp + i);
                a[i+0][j] = v.x; a[i+1][j] = v.y; a[i+2][j] = v.z; a[i+3][j] = v.w;
            }
        }

        int used = 0;

        for (int k = 0; k < 256; ++k) {
            const int wvk = k >> 5, ikk = k & 31, buf = k & 1;

            if (wv == wvk) {
                float c0, c1, c2, c3;
#define EXT(I) { c0 = a[I][0]; c1 = a[I][1]; c2 = a[I][2]; c3 = a[I][3]; }
                switch (ikk) { COL_CASES(EXT) }
#undef EXT
                // packed-key argmax over unused rows, pure-VALU DPP reduce
                unsigned key = (used & 1) ? 0u : pkey(c0, ct*4 + 0);
                unsigned q1  = (used & 2) ? 0u : pkey(c1, ct*4 + 1); key = key > q1 ? key : q1;
                unsigned q2  = (used & 4) ? 0u : pkey(c2, ct*4 + 2); key = key > q2 ? key : q2;
                unsigned q3  = (used & 8) ? 0u : pkey(c3, ct*4 + 3); key = key > q3 ? key : q3;
                key = dpp_umax64_lane63(key);
                const int pn = __builtin_amdgcn_readlane((int)key, 63) & 255;
                float bv;
                switch (pn & 3) {
                    case 0: bv = rlf(c0, pn >> 2); break;
                    case 1: bv = rlf(c1, pn >> 2); break;
                    case 2: bv = rlf(c2, pn >> 2); break;
                    default: bv = rlf(c3, pn >> 2); break;
                }
                float4 cw; cw.x = c0; cw.y = c1; cw.z = c2; cw.w = c3;
                *(float4*)(&colv[buf][ct*4]) = cw;
                if (ct == 0) {
                    s_p[buf] = pn;
                    s_pv[buf] = 1.0f / bv;
                    pivrow[k] = pn;
                }
            }
            __syncthreads();

            const int   p      = __builtin_amdgcn_readfirstlane(s_p[buf]);
            const float pivinv = s_pv[buf];
            const int ctp = p >> 2, jp = p & 3;

            const float4 dv = *(const float4*)(&colv[buf][ct*4]);

            // pivot-row broadcast via v_readlane (VALU pipe; no ds_bpermute)
            float prw[32];
#define BRD(J) { _Pragma("unroll") for (int i = 0; i < 32; ++i) \
                    prw[i] = rlf(a[i][J], ctp) * pivinv; }
            switch (jp) {
                case 0: BRD(0) break; case 1: BRD(1) break;
                case 2: BRD(2) break; default: BRD(3) break;
            }
#undef BRD

            if (wv == wvk) {   // column-k special case ONLY in the owning wave
#define ZCOL(I) { prw[I] = pivinv; a[I][0] = 0.0f; a[I][1] = 0.0f; a[I][2] = 0.0f; a[I][3] = 0.0f; }
                switch (ikk) { COL_CASES(ZCOL) }
#undef ZCOL
            }

            const float d0 = -dv.x, d1 = -dv.y, d2 = -dv.z, d3 = -dv.w;
#pragma unroll
            for (int i = 0; i < 32; ++i) {
                const float pw = prw[i];
                a[i][0] = fmaf(d0, pw, a[i][0]);
                a[i][1] = fmaf(d1, pw, a[i][1]);
                a[i][2] = fmaf(d2, pw, a[i][2]);
                a[i][3] = fmaf(d3, pw, a[i][3]);
            }

            const bool mine = (ct == ctp);
#define OWR(J) { _Pragma("unroll") for (int i = 0; i < 32; ++i) a[i][J] = mine ? prw[i] : a[i][J]; }
            switch (jp) {
                case 0: OWR(0) break; case 1: OWR(1) break;
                case 2: OWR(2) break; default: OWR(3) break;
            }
#undef OWR
            if (mine) used |= (1 << jp);
        }
        __syncthreads();

        // stored a[i][j] = M[r][c], r = ilog[ct*4+j], c = pivrow[wv*32+i]
        if (tid < 256) { ilogrow[pivrow[tid]] = tid; qs[tid] = qg[(size_t)layer*NU + tid]; }
        __syncthreads();

        // ---- bq = M q ----
        {
            float s0=0.f, s1=0.f, s2=0.f, s3=0.f;
#pragma unroll
            for (int i = 0; i < 32; ++i) {
                const float qq = qs[pivrow[wv*32 + i]];
                s0 = fmaf(a[i][0], qq, s0);
                s1 = fmaf(a[i][1], qq, s1);
                s2 = fmaf(a[i][2], qq, s2);
                s3 = fmaf(a[i][3], qq, s3);
            }
            part[wv][ct*4+0] = s0; part[wv][ct*4+1] = s1;
            part[wv][ct*4+2] = s2; part[wv][ct*4+3] = s3;
        }
        __syncthreads();
        if (tid < 256) {
            float s = 0.f;
#pragma unroll
            for (int w2 = 0; w2 < 8; ++w2) s += part[w2][tid];
            bq[(size_t)layer*NU + ilogrow[tid]] = s;
        }

        // ---- split-bf16 W planes ----
        u16* nh = wnnh + (size_t)layer*NUSQ; u16* nl = wnnl + (size_t)layer*NUSQ;
        u16* th = wnth + (size_t)layer*NUSQ; u16* tl = wntl + (size_t)layer*NUSQ;
#pragma unroll
        for (int j = 0; j < 4; ++j) {
            const int r = ilogrow[ct*4 + j];
#pragma unroll
            for (int i = 0; i < 32; ++i) {
                const int c = pivrow[wv*32 + i];
                const float v = a[i][j];
                const u16 h  = f2bf(v);
                const u16 lo = f2bf(v - bf2f(h));
                th[(size_t)r*NU + c] = h;  tl[(size_t)r*NU + c] = lo;  // wnt[n][k]=M[n][k]
                nh[(size_t)c*NU + r] = h;  nl[(size_t)c*NU + r] = lo;  // wnn[n][k]=M[k][n]
            }
        }
        return;
    }

    // =================== in_gemm path (256 active threads) ===================
    if (tid >= 256) return;   // exited waves free their slots; HW barrier counts rest

    const int bid = blockIdx.x - NLAYERS;
    const int m0 = (bid & 255) * 128;
    const int n0 = (bid >> 8) * 128;
    const int t  = tid;
    const int tx = t & 15, ty = t >> 4;
    const int K = NDIN;

    float acc[8][8];
#pragma unroll
    for (int i = 0; i < 8; ++i)
#pragma unroll
        for (int j = 0; j < 8; ++j) acc[i][j] = 0.0f;

    const int am = t >> 1;
    const int ak = (t & 1) * 8;
    const int bk = t >> 4;
    const int bn = (t & 15) * 8;

    for (int k0 = 0; k0 < K; k0 += 16) {
        const float* Ap = X + (size_t)(m0 + am)*K + (k0 + ak);
        const float4 a0 = *(const float4*)(Ap);
        const float4 a1 = *(const float4*)(Ap + 4);
        As[ak+0][am] = a0.x; As[ak+1][am] = a0.y; As[ak+2][am] = a0.z; As[ak+3][am] = a0.w;
        As[ak+4][am] = a1.x; As[ak+5][am] = a1.y; As[ak+6][am] = a1.z; As[ak+7][am] = a1.w;
        const float* Bp = Win + (size_t)(k0 + bk)*NU + (n0 + bn);
        const float4 b0 = *(const float4*)(Bp);
        const float4 b1 = *(const float4*)(Bp + 4);
        *(float4*)(&Bs[bk][bn])   = b0;
        *(float4*)(&Bs[bk][bn+4]) = b1;
        __syncthreads();
#pragma unroll
        for (int kk = 0; kk < 16; ++kk) {
            float af[8], bf[8];
            *(float4*)(af)   = *(const float4*)(&As[kk][ty*8]);
            *(float4*)(af+4) = *(const float4*)(&As[kk][ty*8+4]);
            *(float4*)(bf)   = *(const float4*)(&Bs[kk][tx*8]);
            *(float4*)(bf+4) = *(const float4*)(&Bs[kk][tx*8+4]);
#pragma unroll
            for (int i = 0; i < 8; ++i)
#pragma unroll
                for (int j = 0; j < 8; ++j)
                    acc[i][j] = fmaf(af[i], bf[j], acc[i][j]);
        }
        __syncthreads();
    }

#pragma unroll
    for (int i = 0; i < 8; ++i) {
        const size_t row = m0 + ty*8 + i;
        s16x8 vh, vl, th2, tl2;
#pragma unroll
        for (int j = 0; j < 8; ++j) {
            const float v = acc[i][j] + bin[n0 + tx*8 + j];
            const u16 h  = f2bf(v);
            vh[j] = (short)h; vl[j] = (short)f2bf(v - bf2f(h));
            const float tv = tanhf(v);
            const u16 h2 = f2bf(tv);
            th2[j] = (short)h2; tl2[j] = (short)f2bf(tv - bf2f(h2));
        }
        const size_t o = row*NU + n0 + tx*8;
        *(s16x8*)&V0h[o] = vh; *(s16x8*)&V0l[o] = vl;
        *(s16x8*)&V1h[o] = th2; *(s16x8*)&V1l[o] = tl2;
    }
}

// ---------------------------------------------------------------------------
// Split-bf16 MFMA GEMM: C(32768x256) = alpha * A @ W (+bias). Staging via
// async global_load_lds width=16 (lane-contiguous LDS mapping: thread t <->
// LDS bytes [16t,16t+16) per plane buffer). 128x128 tile, BK=32, 4 waves,
// wave = 64x64 = 4x4 MFMA 16x16x32. Split product hh + hl + lh.
// ---------------------------------------------------------------------------
__global__ __launch_bounds__(256, 2) void gemm_mfma(
    const u16* __restrict__ Ah, const u16* __restrict__ Al,
    const u16* __restrict__ Bh, const u16* __restrict__ Bl,
    u16* __restrict__ Ch, u16* __restrict__ Cl,
    const float* __restrict__ bias, const float alpha)
{
    __shared__ __align__(16) u16 lAh[128*32], lAl[128*32], lBh[128*32], lBl[128*32];
    const int t    = threadIdx.x;
    const int lane = t & 63;
    const int w    = t >> 6;
    const int wr = w >> 1, wc = w & 1;
    const int qd = lane >> 4, l15 = lane & 15;
    const int m0 = blockIdx.x * 128, n0 = blockIdx.y * 128;

    const int srow = t >> 2;          // 0..63
    const int skc  = (t & 3) * 8;     // 0,8,16,24

    f32x4 acc[4][4];
    const f32x4 z = {0.f, 0.f, 0.f, 0.f};
#pragma unroll
    for (int i = 0; i < 4; ++i)
#pragma unroll
        for (int j = 0; j < 4; ++j) acc[i][j] = z;

    for (int k0 = 0; k0 < NU; k0 += 32) {
#pragma unroll
        for (int half = 0; half < 2; ++half) {
            const int rr = srow + half*64;
            const size_t ga = (size_t)(m0 + rr)*NU + k0 + skc;
            const size_t gb = (size_t)(n0 + rr)*NU + k0 + skc;
            const int lo = rr*32 + skc;
            gl_lds16(Ah + ga, &lAh[lo]);
            gl_lds16(Al + ga, &lAl[lo]);
            gl_lds16(Bh + gb, &lBh[lo]);
            gl_lds16(Bl + gb, &lBl[lo]);
        }
        __syncthreads();

        s16x8 ah[4], al[4], bh[4], bl[4];
#pragma unroll
        for (int mt = 0; mt < 4; ++mt) {
            const int off = (wr*64 + mt*16 + l15)*32 + qd*8;
            ah[mt] = *(const s16x8*)&lAh[off];
            al[mt] = *(const s16x8*)&lAl[off];
        }
#pragma unroll
        for (int nt = 0; nt < 4; ++nt) {
            const int off = (wc*64 + nt*16 + l15)*32 + qd*8;
            bh[nt] = *(const s16x8*)&lBh[off];
            bl[nt] = *(const s16x8*)&lBl[off];
        }
#pragma unroll
        for (int mt = 0; mt < 4; ++mt)
#pragma unroll
            for (int nt = 0; nt < 4; ++nt) {
                acc[mt][nt] = __builtin_amdgcn_mfma_f32_16x16x32_bf16(ah[mt], bh[nt], acc[mt][nt], 0, 0, 0);
                acc[mt][nt] = __builtin_amdgcn_mfma_f32_16x16x32_bf16(ah[mt], bl[nt], acc[mt][nt], 0, 0, 0);
                acc[mt][nt] = __builtin_amdgcn_mfma_f32_16x16x32_bf16(al[mt], bh[nt], acc[mt][nt], 0, 0, 0);
            }
        __syncthreads();
    }

#pragma unroll
    for (int mt = 0; mt < 4; ++mt) {
#pragma unroll
        for (int nt = 0; nt < 4; ++nt) {
            const int col = n0 + wc*64 + nt*16 + l15;
            const float bb = bias ? bias[col] : 0.0f;
#pragma unroll
            for (int r = 0; r < 4; ++r) {
                const int row = m0 + wr*64 + mt*16 + qd*4 + r;
                const float v = alpha*acc[mt][nt][r] + bb;
                const u16 h  = f2bf(v);
                const u16 lo = f2bf(v - bf2f(h));
                const size_t o = (size_t)row*NU + col;
                Ch[o] = h; Cl[o] = lo;
            }
        }
    }
}

// ---------------------------------------------------------------------------
// out = V0 @ W_out + b_out, N=10. One wave per batch row; V0 from planes.
// ---------------------------------------------------------------------------
__global__ __launch_bounds__(256) void out_gemm(
    const u16* __restrict__ V0h, const u16* __restrict__ V0l,
    const float* __restrict__ Wout,
    const float* __restrict__ bout, float* __restrict__ out)
{
    __shared__ float Ws[NU*NDOUT];
    const int t = threadIdx.x;
    for (int i = t; i < NU*NDOUT; i += 256) Ws[i] = Wout[i];
    __syncthreads();
    const int lane = t & 63;
    const int wv = t >> 6;
    const int row = blockIdx.x*4 + wv;
    float acc[NDOUT];
#pragma unroll
    for (int j = 0; j < NDOUT; ++j) acc[j] = 0.0f;
#pragma unroll
    for (int s = 0; s < 4; ++s) {
        const int k = lane + 64*s;
        const size_t o = (size_t)row*NU + k;
        const float v = bf2f(V0h[o]) + bf2f(V0l[o]);
#pragma unroll
        for (int j = 0; j < NDOUT; ++j) acc[j] = fmaf(v, Ws[k*NDOUT + j], acc[j]);
    }
#pragma unroll
    for (int off = 32; off > 0; off >>= 1) {
#pragma unroll
        for (int j = 0; j < NDOUT; ++j) acc[j] += __shfl_down(acc[j], off);
    }
    if (lane == 0) {
#pragma unroll
        for (int j = 0; j < NDOUT; ++j) out[(size_t)row*NDOUT + j] = acc[j] + bout[j];
    }
}

extern "C" void kernel_launch(void* const* d_in, const int* in_sizes, int n_in,
                              void* d_out, int out_size, void* d_ws, size_t ws_size,
                              hipStream_t stream)
{
    const float* x    = (const float*)d_in[0];
    const float* Win  = (const float*)d_in[1];
    const float* bin  = (const float*)d_in[2];
    const float* B0   = (const float*)d_in[3];
    const float* q    = (const float*)d_in[4];
    const float* Wout = (const float*)d_in[5];
    const float* bout = (const float*)d_in[6];
    float* out = (float*)d_out;

    // workspace carve (~104 MB)
    u16* wnnh = (u16*)d_ws;
    u16* wnnl = wnnh + (size_t)NLAYERS*NUSQ;
    u16* wnth = wnnl + (size_t)NLAYERS*NUSQ;
    u16* wntl = wnth + (size_t)NLAYERS*NUSQ;
    float* bq = (float*)(wntl + (size_t)NLAYERS*NUSQ);
    u16* pl   = (u16*)(bq + NLAYERS*NU);
    const size_t PSZ = (size_t)NBATCH*NU;
    u16* sAh = pl;           u16* sAl = sAh + PSZ;   // slot A (V0)
    u16* sBh = sAl + PSZ;    u16* sBl = sBh + PSZ;   // slot B (V1)
    u16* sCh = sBl + PSZ;    u16* sCl = sCh + PSZ;   // slot C (free)

    // fused: 6 invert blocks + 512 in_gemm blocks, concurrent
    fused_inv_ingemm<<<NLAYERS + 512, 512, 0, stream>>>(
        B0, q, wnnh, wnnl, wnth, wntl, bq,
        x, Win, bin, sAh, sAl, sBh, sBl);

    const dim3 ggrid(NBATCH/128, NU/128);   // 256 x 2

    u16 *v0h = sAh, *v0l = sAl, *v1h = sBh, *v1l = sBl, *frh = sCh, *frl = sCl;
    for (int l = 0; l < NLAYERS; ++l) {
        const size_t wo = (size_t)l*NUSQ;
        // newV0 = -V1 @ M
        gemm_mfma<<<ggrid, 256, 0, stream>>>(v1h, v1l, wnnh + wo, wnnl + wo,
                                             frh, frl, nullptr, -1.0f);
        // newV1 = V0 @ M^T + (Mq)^T
        gemm_mfma<<<ggrid, 256, 0, stream>>>(v0h, v0l, wnth + wo, wntl + wo,
                                             v1h, v1l, bq + (size_t)l*NU, 1.0f);
        u16* t0 = v0h; u16* t1 = v0l;
        v0h = frh; v0l = frl; frh = t0; frl = t1;
    }
    out_gemm<<<NBATCH/4, 256, 0, stream>>>(v0h, v0l, Wout, bout, out);
}